// Round 7
// baseline (162.706 us; speedup 1.0000x reference)
//
#include <hip/hip_runtime.h>

#define B_ROWS 4096
#define N_ROWS 8192
#define DDIM   1024
#define DELTA_M 0.2f
#define EPSF    1e-8f

#define BK3 32
#define NW  (DDIM / BK3)   // 32 windows

typedef short bf16x8 __attribute__((ext_vector_type(8)));
typedef float f32x4 __attribute__((ext_vector_type(4)));

__device__ inline unsigned short f32_to_bf16(float f) {
    unsigned int u = __float_as_uint(f);
    u += 0x7FFFu + ((u >> 16) & 1u);   // round-to-nearest-even
    return (unsigned short)(u >> 16);
}

__device__ inline void load_lds16(const void* g, void* l) {
    __builtin_amdgcn_global_load_lds(
        (const __attribute__((address_space(1))) void*)g,
        (__attribute__((address_space(3))) void*)l,
        16, 0, 0);
}

// ---------------- norm (+ out zeroing; memset dispatch removed) ----------------
__global__ __launch_bounds__(256)
void norm_kernel(const float* __restrict__ q, const float* __restrict__ k,
                 const float* __restrict__ queue,
                 unsigned short* __restrict__ qn,
                 unsigned short* __restrict__ qun,
                 float* __restrict__ pos, float* __restrict__ out) {
    const int tid  = threadIdx.x;
    const int lane = tid & 63;
    const int wave = tid >> 6;
    const int row  = blockIdx.x * 4 + wave;
    if (blockIdx.x == 0 && tid == 0) *out = 0.f;

    if (row < B_ROWS) {
        const float4* qr = reinterpret_cast<const float4*>(q + (size_t)row * DDIM);
        const float4* kr = reinterpret_cast<const float4*>(k + (size_t)row * DDIM);
        float4 a[4], b[4];
        #pragma unroll
        for (int j = 0; j < 4; ++j) a[j] = qr[lane + j * 64];
        #pragma unroll
        for (int j = 0; j < 4; ++j) b[j] = kr[lane + j * 64];
        float s11 = 0.f, s22 = 0.f, s12 = 0.f;
        #pragma unroll
        for (int j = 0; j < 4; ++j) {
            s11 += a[j].x * a[j].x + a[j].y * a[j].y + a[j].z * a[j].z + a[j].w * a[j].w;
            s22 += b[j].x * b[j].x + b[j].y * b[j].y + b[j].z * b[j].z + b[j].w * b[j].w;
            s12 += a[j].x * b[j].x + a[j].y * b[j].y + a[j].z * b[j].z + a[j].w * b[j].w;
        }
        #pragma unroll
        for (int off = 1; off < 64; off <<= 1) {
            s11 += __shfl_xor(s11, off);
            s22 += __shfl_xor(s22, off);
            s12 += __shfl_xor(s12, off);
        }
        const float inv1 = 1.0f / fmaxf(sqrtf(s11), EPSF);
        const float inv2 = 1.0f / fmaxf(sqrtf(s22), EPSF);
        if (lane == 0) pos[row] = s12 * inv1 * inv2;
        ushort4* orow = reinterpret_cast<ushort4*>(qn + (size_t)row * DDIM);
        #pragma unroll
        for (int j = 0; j < 4; ++j) {
            ushort4 o;
            o.x = f32_to_bf16(a[j].x * inv1);
            o.y = f32_to_bf16(a[j].y * inv1);
            o.z = f32_to_bf16(a[j].z * inv1);
            o.w = f32_to_bf16(a[j].w * inv1);
            orow[lane + j * 64] = o;
        }
    } else {
        const int r2 = row - B_ROWS;
        const float4* qr = reinterpret_cast<const float4*>(queue + (size_t)r2 * DDIM);
        float4 a[4];
        #pragma unroll
        for (int j = 0; j < 4; ++j) a[j] = qr[lane + j * 64];
        float s11 = 0.f;
        #pragma unroll
        for (int j = 0; j < 4; ++j)
            s11 += a[j].x * a[j].x + a[j].y * a[j].y + a[j].z * a[j].z + a[j].w * a[j].w;
        #pragma unroll
        for (int off = 1; off < 64; off <<= 1) s11 += __shfl_xor(s11, off);
        const float inv1 = 1.0f / fmaxf(sqrtf(s11), EPSF);
        ushort4* orow = reinterpret_cast<ushort4*>(qun + (size_t)r2 * DDIM);
        #pragma unroll
        for (int j = 0; j < 4; ++j) {
            ushort4 o;
            o.x = f32_to_bf16(a[j].x * inv1);
            o.y = f32_to_bf16(a[j].y * inv1);
            o.z = f32_to_bf16(a[j].z * inv1);
            o.w = f32_to_bf16(a[j].w * inv1);
            orow[lane + j * 64] = o;
        }
    }
}

// ---------------- 256x256 GEMM, 16 waves (4x4), BK=32 dbuf, + fused hinge ----
// Per wave: 64x64 output -> acc[4][4] f32x4 = 64 VGPR  => 4 waves/SIMD.
// LDS 64KB: buf p at p*32768: A [256r][32k] (16KB) then B [256c][32k] (16KB).
// Row stride 64B; swizzle phys = logical ^ (((logical>>7)&3)<<4)
//   (XOR chunk bits [5:4] with row bits [2:1]; involution; 16B-preserving;
//    residual 2-way LDS aliasing = free [m136]).
// Staging (rule #21): linear dest d = tid*16 (1024 thr x 16B = 16KB = whole
//   region, 1 load/thread/region); source = logical elem at d ^ (((d>>7)&3)<<4).
// Window T:  issue 8 ds_reads (buf cur) ; lgkmcnt(0) ; s_barrier#1
//            [all waves' reads of buf cur done -> overwrite safe]
//            stage T+2 -> buf cur (2 gloads) ; 16 MFMA (hides stage issue)
//            vmcnt(2) [T+1's 2 loads landed; T+2's 2 in flight] ; s_barrier#2
//            [all waves' T+1 stages landed -> next window may read]
// Tail: T=30: no stage, vmcnt(0). T=31: no stage, no wait (epilogue syncs).
__device__ __forceinline__ void stage_pair(const unsigned short* srcA,
                                           const unsigned short* srcB,
                                           int k0, unsigned char* bufA, int t16) {
    load_lds16(srcA + k0, bufA + t16);            // A region
    load_lds16(srcB + k0, bufA + 16384 + t16);    // B region
}

template<bool STG, int WE>
__device__ __forceinline__ void gemm_window(
    int T, unsigned char* lds,
    const unsigned short* srcA, const unsigned short* srcB,
    int aBase, int bBase, int t16, f32x4 (&acc)[4][4]) {

    const int par = T & 1;
    unsigned char* buf = lds + par * 32768;

    bf16x8 a[4], b[4];
    #pragma unroll
    for (int fm = 0; fm < 4; ++fm)
        a[fm] = *reinterpret_cast<const bf16x8*>(&buf[aBase + fm * 1024]);
    #pragma unroll
    for (int fn = 0; fn < 4; ++fn)
        b[fn] = *reinterpret_cast<const bf16x8*>(&buf[16384 + bBase + fn * 1024]);
    asm volatile("s_waitcnt lgkmcnt(0)" ::: "memory");
    __builtin_amdgcn_sched_barrier(0);
    __builtin_amdgcn_s_barrier();                 // #1: block-wide reads done

    if (STG)
        stage_pair(srcA, srcB, (T + 2) * BK3, buf, t16);

    __builtin_amdgcn_s_setprio(1);
    #pragma unroll
    for (int fm = 0; fm < 4; ++fm)
        #pragma unroll
        for (int fn = 0; fn < 4; ++fn)
            acc[fm][fn] = __builtin_amdgcn_mfma_f32_16x16x32_bf16(
                a[fm], b[fn], acc[fm][fn], 0, 0, 0);
    __builtin_amdgcn_s_setprio(0);

    if (WE >= 0) {
        if (WE == 2)      asm volatile("s_waitcnt vmcnt(2)" ::: "memory");
        else              asm volatile("s_waitcnt vmcnt(0)" ::: "memory");
        __builtin_amdgcn_sched_barrier(0);
        __builtin_amdgcn_s_barrier();             // #2: T+1 buffer published
    }
}

__global__ __launch_bounds__(1024, 4)
void gemm_hinge(const unsigned short* __restrict__ A,
                const unsigned short* __restrict__ Bq,
                const float* __restrict__ pos,
                float* __restrict__ out) {
    __shared__ __align__(16) unsigned char lds[65536];

    const int tid  = threadIdx.x;
    const int lane = tid & 63;
    const int wave = tid >> 6;

    // XCD map: grid 512 = 16 bm x 32 bn tiles; 8x8 tile square per XCD.
    const int bid = blockIdx.x;
    const int x   = bid & 7;
    const int idx = bid >> 3;
    const int bm = ((x & 1) * 8 + (idx & 7)) * 256;
    const int bn = ((x >> 1) * 8 + (idx >> 3)) * 256;

    const int wr = wave >> 2, wc = wave & 3;      // 4x4 waves, 64x64 each
    const int ln15 = lane & 15, kq = lane >> 4;
    const int kqoff = (kq * 16) ^ (((ln15 >> 1) & 3) << 4);
    const int aBase = (wr * 64 + ln15) * 64 + kqoff;
    const int bBase = (wc * 64 + ln15) * 64 + kqoff;

    // staging source (pre-unswizzled global address)
    const int t16 = tid * 16;
    const int l   = t16 ^ (((t16 >> 7) & 3) << 4);
    const int sr  = l >> 6;
    const int sc  = (l & 63) >> 1;
    const unsigned short* srcA = A  + (size_t)(bm + sr) * DDIM + sc;
    const unsigned short* srcB = Bq + (size_t)(bn + sr) * DDIM + sc;

    f32x4 acc[4][4];
    #pragma unroll
    for (int fm = 0; fm < 4; ++fm)
        #pragma unroll
        for (int fn = 0; fn < 4; ++fn)
            acc[fm][fn] = (f32x4){0.f, 0.f, 0.f, 0.f};

    // prologue: windows 0 -> buf0, 1 -> buf1 (per-thread issue order A,B,A,B)
    stage_pair(srcA, srcB, 0,   lds,         t16);
    stage_pair(srcA, srcB, BK3, lds + 32768, t16);
    asm volatile("s_waitcnt vmcnt(2)" ::: "memory");   // window 0 landed
    __builtin_amdgcn_sched_barrier(0);
    __builtin_amdgcn_s_barrier();

    #pragma unroll 1
    for (int T = 0; T < NW - 2; ++T)
        gemm_window<true, 2>(T, lds, srcA, srcB, aBase, bBase, t16, acc);
    gemm_window<false, 0>(NW - 2, lds, srcA, srcB, aBase, bBase, t16, acc);
    gemm_window<false, -1>(NW - 1, lds, srcA, srcB, aBase, bBase, t16, acc);

    // ---- fused hinge epilogue ----
    // C/D: row = bm + wr*64 + fm*16 + kq*4 + j ; col = bn + wc*64 + fn*16 + ln15
    float lsum = 0.f;
    #pragma unroll
    for (int fm = 0; fm < 4; ++fm) {
        const float4 p4 = *reinterpret_cast<const float4*>(
            pos + bm + wr * 64 + fm * 16 + kq * 4);
        const float pj[4] = {p4.x, p4.y, p4.z, p4.w};
        #pragma unroll
        for (int fn = 0; fn < 4; ++fn)
            #pragma unroll
            for (int j = 0; j < 4; ++j)
                lsum += fmaxf(DELTA_M - pj[j] + acc[fm][fn][j], 0.f);
    }
    #pragma unroll
    for (int off = 32; off; off >>= 1) lsum += __shfl_down(lsum, off);
    __syncthreads();                    // all windows consumed; LDS reusable
    float* red = reinterpret_cast<float*>(lds);
    if (lane == 0) red[wave] = lsum;
    __syncthreads();
    if (tid == 0) {
        float s = 0.f;
        #pragma unroll
        for (int w = 0; w < 16; ++w) s += red[w];
        atomicAdd(out, s);
    }
}

extern "C" void kernel_launch(void* const* d_in, const int* in_sizes, int n_in,
                              void* d_out, int out_size, void* d_ws, size_t ws_size,
                              hipStream_t stream) {
    const float* q     = (const float*)d_in[0];
    const float* k     = (const float*)d_in[1];
    const float* queue = (const float*)d_in[2];
    float* out = (float*)d_out;

    unsigned short* qn  = (unsigned short*)d_ws;
    unsigned short* qun = qn + (size_t)B_ROWS * DDIM;
    float* pos = (float*)(qun + (size_t)N_ROWS * DDIM);

    norm_kernel<<<(B_ROWS + N_ROWS) / 4, 256, 0, stream>>>(q, k, queue, qn, qun, pos, out);
    gemm_hinge<<<(B_ROWS / 256) * (N_ROWS / 256), 1024, 0, stream>>>(qn, qun, pos, out);
}

// Round 8
// 155.365 us; speedup vs baseline: 1.0473x; 1.0473x over previous
//
#include <hip/hip_runtime.h>

#define B_ROWS 4096
#define N_ROWS 8192
#define DDIM   1024
#define DELTA_M 0.2f
#define EPSF    1e-8f

#define BK3 32
#define NW  (DDIM / BK3)   // 32 windows

typedef short bf16x8 __attribute__((ext_vector_type(8)));
typedef float f32x4 __attribute__((ext_vector_type(4)));

__device__ inline unsigned short f32_to_bf16(float f) {
    unsigned int u = __float_as_uint(f);
    u += 0x7FFFu + ((u >> 16) & 1u);   // round-to-nearest-even
    return (unsigned short)(u >> 16);
}

__device__ inline void load_lds16(const void* g, void* l) {
    __builtin_amdgcn_global_load_lds(
        (const __attribute__((address_space(1))) void*)g,
        (__attribute__((address_space(3))) void*)l,
        16, 0, 0);
}

// ---------------- norm (+ out zeroing) ----------------
__global__ __launch_bounds__(256)
void norm_kernel(const float* __restrict__ q, const float* __restrict__ k,
                 const float* __restrict__ queue,
                 unsigned short* __restrict__ qn,
                 unsigned short* __restrict__ qun,
                 float* __restrict__ pos, float* __restrict__ out) {
    const int tid  = threadIdx.x;
    const int lane = tid & 63;
    const int wave = tid >> 6;
    const int row  = blockIdx.x * 4 + wave;
    if (blockIdx.x == 0 && tid == 0) *out = 0.f;

    if (row < B_ROWS) {
        const float4* qr = reinterpret_cast<const float4*>(q + (size_t)row * DDIM);
        const float4* kr = reinterpret_cast<const float4*>(k + (size_t)row * DDIM);
        float4 a[4], b[4];
        #pragma unroll
        for (int j = 0; j < 4; ++j) a[j] = qr[lane + j * 64];
        #pragma unroll
        for (int j = 0; j < 4; ++j) b[j] = kr[lane + j * 64];
        float s11 = 0.f, s22 = 0.f, s12 = 0.f;
        #pragma unroll
        for (int j = 0; j < 4; ++j) {
            s11 += a[j].x * a[j].x + a[j].y * a[j].y + a[j].z * a[j].z + a[j].w * a[j].w;
            s22 += b[j].x * b[j].x + b[j].y * b[j].y + b[j].z * b[j].z + b[j].w * b[j].w;
            s12 += a[j].x * b[j].x + a[j].y * b[j].y + a[j].z * b[j].z + a[j].w * b[j].w;
        }
        #pragma unroll
        for (int off = 1; off < 64; off <<= 1) {
            s11 += __shfl_xor(s11, off);
            s22 += __shfl_xor(s22, off);
            s12 += __shfl_xor(s12, off);
        }
        const float inv1 = 1.0f / fmaxf(sqrtf(s11), EPSF);
        const float inv2 = 1.0f / fmaxf(sqrtf(s22), EPSF);
        if (lane == 0) pos[row] = s12 * inv1 * inv2;
        ushort4* orow = reinterpret_cast<ushort4*>(qn + (size_t)row * DDIM);
        #pragma unroll
        for (int j = 0; j < 4; ++j) {
            ushort4 o;
            o.x = f32_to_bf16(a[j].x * inv1);
            o.y = f32_to_bf16(a[j].y * inv1);
            o.z = f32_to_bf16(a[j].z * inv1);
            o.w = f32_to_bf16(a[j].w * inv1);
            orow[lane + j * 64] = o;
        }
    } else {
        const int r2 = row - B_ROWS;
        const float4* qr = reinterpret_cast<const float4*>(queue + (size_t)r2 * DDIM);
        float4 a[4];
        #pragma unroll
        for (int j = 0; j < 4; ++j) a[j] = qr[lane + j * 64];
        float s11 = 0.f;
        #pragma unroll
        for (int j = 0; j < 4; ++j)
            s11 += a[j].x * a[j].x + a[j].y * a[j].y + a[j].z * a[j].z + a[j].w * a[j].w;
        #pragma unroll
        for (int off = 1; off < 64; off <<= 1) s11 += __shfl_xor(s11, off);
        const float inv1 = 1.0f / fmaxf(sqrtf(s11), EPSF);
        ushort4* orow = reinterpret_cast<ushort4*>(qun + (size_t)r2 * DDIM);
        #pragma unroll
        for (int j = 0; j < 4; ++j) {
            ushort4 o;
            o.x = f32_to_bf16(a[j].x * inv1);
            o.y = f32_to_bf16(a[j].y * inv1);
            o.z = f32_to_bf16(a[j].z * inv1);
            o.w = f32_to_bf16(a[j].w * inv1);
            orow[lane + j * 64] = o;
        }
    }
}

// ---------------- 256x256 GEMM, 8 waves (2x4), wave tile 128x64 ----------------
// 3 LDS buffers (32KB each: A [256r][32k] @+0, B [256c][32k] @+16384), 96KB.
// Swizzle: phys = logical ^ (((logical>>7)&3)<<4)  (64B rows; involution;
//   2-way residual = free). Staging pre-unswizzles the global source (rule #21).
// Window T (ONE barrier):
//   issue 12 ds_reads: tile T+1 frags from buf[(T+1)%3] -> nxt regs
//   issue 4 gload_lds: tile T+3 -> buf[T%3]  (tile T's reads completed last window)
//   32 MFMA on `use` regs (tile T)           <- LDS + VMEM drain under this
//   vmcnt(4)  [T+2 landed; T+3 in flight] ; lgkmcnt(0) [nxt ready] ; s_barrier
// No read/write alias: reads touch (T+1)%3; in-flight writes touch T%3,(T+2)%3.
// Tail: T=29 vmcnt(0); T=30 lgkm-only (no barrier); T=31 MFMA-only.
struct Frags { bf16x8 a[8]; bf16x8 b[4]; };

__device__ __forceinline__ void ld_frags(const unsigned char* buf, int aBase, int bBase,
                                         Frags& f) {
    #pragma unroll
    for (int fm = 0; fm < 8; ++fm)
        f.a[fm] = *reinterpret_cast<const bf16x8*>(&buf[aBase + fm * 1024]);
    #pragma unroll
    for (int fn = 0; fn < 4; ++fn)
        f.b[fn] = *reinterpret_cast<const bf16x8*>(&buf[16384 + bBase + fn * 1024]);
}

__device__ __forceinline__ void do_mfma(const Frags& f, f32x4 (&acc)[8][4]) {
    __builtin_amdgcn_s_setprio(1);
    #pragma unroll
    for (int fm = 0; fm < 8; ++fm)
        #pragma unroll
        for (int fn = 0; fn < 4; ++fn)
            acc[fm][fn] = __builtin_amdgcn_mfma_f32_16x16x32_bf16(
                f.a[fm], f.b[fn], acc[fm][fn], 0, 0, 0);
    __builtin_amdgcn_s_setprio(0);
}

__device__ __forceinline__ void stage(const unsigned short* sA0, const unsigned short* sA1,
                                      const unsigned short* sB0, const unsigned short* sB1,
                                      int k0, unsigned char* buf, int t16) {
    load_lds16(sA0 + k0, buf + t16);
    load_lds16(sA1 + k0, buf + 8192 + t16);
    load_lds16(sB0 + k0, buf + 16384 + t16);
    load_lds16(sB1 + k0, buf + 24576 + t16);
}

template<bool STG, int WE>   // WE: 4 steady, 0 at T=29, -1 lgkm-only at T=30
__device__ __forceinline__ void window(int T, unsigned char* lds,
    Frags& use, Frags& nxt,
    const unsigned short* sA0, const unsigned short* sA1,
    const unsigned short* sB0, const unsigned short* sB1,
    int aBase, int bBase, int t16, f32x4 (&acc)[8][4]) {

    ld_frags(lds + ((T + 1) % 3) * 32768, aBase, bBase, nxt);
    if (STG)
        stage(sA0, sA1, sB0, sB1, (T + 3) * BK3, lds + (T % 3) * 32768, t16);
    do_mfma(use, acc);
    if (WE == 4)      asm volatile("s_waitcnt vmcnt(4)" ::: "memory");
    else if (WE == 0) asm volatile("s_waitcnt vmcnt(0)" ::: "memory");
    asm volatile("s_waitcnt lgkmcnt(0)" ::: "memory");
    __builtin_amdgcn_sched_barrier(0);
    if (WE >= 0) __builtin_amdgcn_s_barrier();
}

__global__ __launch_bounds__(512, 2)
void gemm_hinge(const unsigned short* __restrict__ A,
                const unsigned short* __restrict__ Bq,
                const float* __restrict__ pos,
                float* __restrict__ out) {
    __shared__ __align__(16) unsigned char lds[98304];

    const int tid  = threadIdx.x;
    const int lane = tid & 63;
    const int wave = tid >> 6;

    // XCD map: grid 512 = 16 bm x 32 bn tiles; 8x8 tile square per XCD.
    const int bid = blockIdx.x;
    const int x   = bid & 7;
    const int idx = bid >> 3;
    const int bm = ((x & 1) * 8 + (idx & 7)) * 256;
    const int bn = ((x >> 1) * 8 + (idx >> 3)) * 256;

    const int wr = wave >> 2, wc = wave & 3;      // 2x4 waves, 128x64 each
    const int ln15 = lane & 15, kq = lane >> 4;
    const int kqoff = (kq * 16) ^ (((ln15 >> 1) & 3) << 4);
    const int aBase = wr * 8192 + ln15 * 64 + kqoff;
    const int bBase = wc * 4096 + ln15 * 64 + kqoff;

    // staging source (pre-unswizzled global address); regions staged in 2 chunks
    const int t16 = tid * 16;
    const int d0 = t16, d1 = t16 + 8192;
    const int l0 = d0 ^ (((d0 >> 7) & 3) << 4);
    const int l1 = d1 ^ (((d1 >> 7) & 3) << 4);
    const int sr0 = l0 >> 6, sc0 = (l0 & 63) >> 1;
    const int sr1 = l1 >> 6, sc1 = (l1 & 63) >> 1;
    const unsigned short* sA0 = A  + (size_t)(bm + sr0) * DDIM + sc0;
    const unsigned short* sA1 = A  + (size_t)(bm + sr1) * DDIM + sc1;
    const unsigned short* sB0 = Bq + (size_t)(bn + sr0) * DDIM + sc0;
    const unsigned short* sB1 = Bq + (size_t)(bn + sr1) * DDIM + sc1;

    f32x4 acc[8][4];
    #pragma unroll
    for (int fm = 0; fm < 8; ++fm)
        #pragma unroll
        for (int fn = 0; fn < 4; ++fn)
            acc[fm][fn] = (f32x4){0.f, 0.f, 0.f, 0.f};

    Frags fA, fB;

    // prologue: stage tiles 0,1,2 -> buf0,1,2 (per-thread order: 4 loads each)
    stage(sA0, sA1, sB0, sB1, 0,       lds,         t16);
    stage(sA0, sA1, sB0, sB1, BK3,     lds + 32768, t16);
    stage(sA0, sA1, sB0, sB1, 2 * BK3, lds + 65536, t16);
    asm volatile("s_waitcnt vmcnt(8)" ::: "memory");   // tile 0 landed
    __builtin_amdgcn_sched_barrier(0);
    __builtin_amdgcn_s_barrier();                      // tile 0 published
    ld_frags(lds, aBase, bBase, fA);                   // tile 0 frags
    asm volatile("s_waitcnt vmcnt(4) lgkmcnt(0)" ::: "memory");  // tile 1 landed; fA ready
    __builtin_amdgcn_sched_barrier(0);
    __builtin_amdgcn_s_barrier();                      // tile 1 published

    #pragma unroll 1
    for (int T = 0; T < 28; T += 2) {
        window<true, 4>(T,     lds, fA, fB, sA0, sA1, sB0, sB1, aBase, bBase, t16, acc);
        window<true, 4>(T + 1, lds, fB, fA, sA0, sA1, sB0, sB1, aBase, bBase, t16, acc);
    }
    window<true,  4>(28, lds, fA, fB, sA0, sA1, sB0, sB1, aBase, bBase, t16, acc);
    window<false, 0>(29, lds, fB, fA, sA0, sA1, sB0, sB1, aBase, bBase, t16, acc);
    window<false,-1>(30, lds, fA, fB, sA0, sA1, sB0, sB1, aBase, bBase, t16, acc);
    do_mfma(fB, acc);                                  // tile 31

    // ---- fused hinge epilogue ----
    // C/D: row = bm + wr*128 + fm*16 + kq*4 + j ; col = bn + wc*64 + fn*16 + ln15
    float lsum = 0.f;
    #pragma unroll
    for (int fm = 0; fm < 8; ++fm) {
        const float4 p4 = *reinterpret_cast<const float4*>(
            pos + bm + wr * 128 + fm * 16 + kq * 4);
        const float pj[4] = {p4.x, p4.y, p4.z, p4.w};
        #pragma unroll
        for (int fn = 0; fn < 4; ++fn)
            #pragma unroll
            for (int j = 0; j < 4; ++j)
                lsum += fmaxf(DELTA_M - pj[j] + acc[fm][fn][j], 0.f);
    }
    #pragma unroll
    for (int off = 32; off; off >>= 1) lsum += __shfl_down(lsum, off);
    __syncthreads();                    // all tiles consumed; LDS reusable
    float* red = reinterpret_cast<float*>(lds);
    if (lane == 0) red[wave] = lsum;
    __syncthreads();
    if (tid == 0) {
        float s = 0.f;
        #pragma unroll
        for (int w = 0; w < 8; ++w) s += red[w];
        atomicAdd(out, s);
    }
}

extern "C" void kernel_launch(void* const* d_in, const int* in_sizes, int n_in,
                              void* d_out, int out_size, void* d_ws, size_t ws_size,
                              hipStream_t stream) {
    const float* q     = (const float*)d_in[0];
    const float* k     = (const float*)d_in[1];
    const float* queue = (const float*)d_in[2];
    float* out = (float*)d_out;

    unsigned short* qn  = (unsigned short*)d_ws;
    unsigned short* qun = qn + (size_t)B_ROWS * DDIM;
    float* pos = (float*)(qun + (size_t)N_ROWS * DDIM);

    norm_kernel<<<(B_ROWS + N_ROWS) / 4, 256, 0, stream>>>(q, k, queue, qn, qun, pos, out);
    gemm_hinge<<<(B_ROWS / 256) * (N_ROWS / 256), 512, 0, stream>>>(qn, qun, pos, out);
}

// Round 9
// 148.087 us; speedup vs baseline: 1.0987x; 1.0491x over previous
//
#include <hip/hip_runtime.h>

#define B_ROWS 4096
#define N_ROWS 8192
#define DDIM   1024
#define DELTA_M 0.2f
#define EPSF    1e-8f

#define NW 32                 // K windows of 32
#define PANEL (256 * DDIM)    // bytes per fp8 panel (256 rows x 1024 k)

typedef float f32x4 __attribute__((ext_vector_type(4)));
typedef unsigned long long u64;

__device__ inline void load_lds16(const void* g, void* l) {
    __builtin_amdgcn_global_load_lds(
        (const __attribute__((address_space(1))) void*)g,
        (__attribute__((address_space(3))) void*)l,
        16, 0, 0);
}

__device__ inline unsigned int pk4(float a, float b, float c, float d) {
    int v = __builtin_amdgcn_cvt_pk_fp8_f32(a, b, 0, false);
    v = __builtin_amdgcn_cvt_pk_fp8_f32(c, d, v, true);
    return (unsigned int)v;
}

// ---------------- norm: f32 -> fp8, written in GEMM-staged panel layout ------
// Panel layout (per 256-row tile): byte = ks*8192 + fm*512 + kq*128 + ln15*8 + e
//   for element (row = fm*16 + ln15, k = ks*32 + kq*8 + e).
// GEMM then stages 8KB slices linearly and ds_read_b64 at frag*512 + lane*8 is
// conflict-free by construction (64 consecutive granules).
__global__ __launch_bounds__(256)
void norm_kernel(const float* __restrict__ q, const float* __restrict__ k,
                 const float* __restrict__ queue,
                 unsigned char* __restrict__ qn,
                 unsigned char* __restrict__ qun,
                 float* __restrict__ pos, float* __restrict__ out) {
    const int tid  = threadIdx.x;
    const int lane = tid & 63;
    const int wave = tid >> 6;
    const int row  = blockIdx.x * 4 + wave;
    if (blockIdx.x == 0 && tid == 0) *out = 0.f;

    // lane covers k = lane*16 .. +16  (float4 indices lane*4 + j)
    if (row < B_ROWS) {
        const float4* qr = reinterpret_cast<const float4*>(q + (size_t)row * DDIM);
        const float4* kr = reinterpret_cast<const float4*>(k + (size_t)row * DDIM);
        float4 a[4], b[4];
        #pragma unroll
        for (int j = 0; j < 4; ++j) a[j] = qr[lane * 4 + j];
        #pragma unroll
        for (int j = 0; j < 4; ++j) b[j] = kr[lane * 4 + j];
        float s11 = 0.f, s22 = 0.f, s12 = 0.f;
        #pragma unroll
        for (int j = 0; j < 4; ++j) {
            s11 += a[j].x * a[j].x + a[j].y * a[j].y + a[j].z * a[j].z + a[j].w * a[j].w;
            s22 += b[j].x * b[j].x + b[j].y * b[j].y + b[j].z * b[j].z + b[j].w * b[j].w;
            s12 += a[j].x * b[j].x + a[j].y * b[j].y + a[j].z * b[j].z + a[j].w * b[j].w;
        }
        #pragma unroll
        for (int off = 1; off < 64; off <<= 1) {
            s11 += __shfl_xor(s11, off);
            s22 += __shfl_xor(s22, off);
            s12 += __shfl_xor(s12, off);
        }
        const float inv1 = 1.0f / fmaxf(sqrtf(s11), EPSF);
        const float inv2 = 1.0f / fmaxf(sqrtf(s22), EPSF);
        if (lane == 0) pos[row] = s12 * inv1 * inv2;
        u64 g0 = (u64)pk4(a[0].x * inv1, a[0].y * inv1, a[0].z * inv1, a[0].w * inv1)
               | ((u64)pk4(a[1].x * inv1, a[1].y * inv1, a[1].z * inv1, a[1].w * inv1) << 32);
        u64 g1 = (u64)pk4(a[2].x * inv1, a[2].y * inv1, a[2].z * inv1, a[2].w * inv1)
               | ((u64)pk4(a[3].x * inv1, a[3].y * inv1, a[3].z * inv1, a[3].w * inv1) << 32);
        const size_t base = (size_t)(row >> 8) * PANEL
                          + (size_t)(lane >> 1) * 8192
                          + (size_t)((row >> 4) & 15) * 512
                          + (size_t)((lane & 1) * 2) * 128
                          + (size_t)(row & 15) * 8;
        *reinterpret_cast<u64*>(qn + base)       = g0;
        *reinterpret_cast<u64*>(qn + base + 128) = g1;
    } else {
        const int r2 = row - B_ROWS;
        const float4* qr = reinterpret_cast<const float4*>(queue + (size_t)r2 * DDIM);
        float4 a[4];
        #pragma unroll
        for (int j = 0; j < 4; ++j) a[j] = qr[lane * 4 + j];
        float s11 = 0.f;
        #pragma unroll
        for (int j = 0; j < 4; ++j)
            s11 += a[j].x * a[j].x + a[j].y * a[j].y + a[j].z * a[j].z + a[j].w * a[j].w;
        #pragma unroll
        for (int off = 1; off < 64; off <<= 1) s11 += __shfl_xor(s11, off);
        const float inv1 = 1.0f / fmaxf(sqrtf(s11), EPSF);
        u64 g0 = (u64)pk4(a[0].x * inv1, a[0].y * inv1, a[0].z * inv1, a[0].w * inv1)
               | ((u64)pk4(a[1].x * inv1, a[1].y * inv1, a[1].z * inv1, a[1].w * inv1) << 32);
        u64 g1 = (u64)pk4(a[2].x * inv1, a[2].y * inv1, a[2].z * inv1, a[2].w * inv1)
               | ((u64)pk4(a[3].x * inv1, a[3].y * inv1, a[3].z * inv1, a[3].w * inv1) << 32);
        const size_t base = (size_t)(r2 >> 8) * PANEL
                          + (size_t)(lane >> 1) * 8192
                          + (size_t)((r2 >> 4) & 15) * 512
                          + (size_t)((lane & 1) * 2) * 128
                          + (size_t)(r2 & 15) * 8;
        *reinterpret_cast<u64*>(qun + base)       = g0;
        *reinterpret_cast<u64*>(qun + base + 128) = g1;
    }
}

// ---------------- 256x256 fp8 GEMM, 8 waves (2x4), wave tile 128x64 ----------
// 3 LDS buffers x 16KB (A frags 8KB @+0, B frags 8KB @+8192) = 48KB.
// Window T (one barrier):
//   12 ds_read_b64: tile T+1 frags (conflict-free, frag*512 + lane*8)
//   2 gload_lds: tile T+3 panel slices -> buf[T%3] (linear copy)
//   32 x mfma_f32_16x16x32_fp8_fp8 on tile T regs
//   vmcnt(2) [T+2 landed, T+3 in flight] ; lgkmcnt(0) ; s_barrier
// Tail: T=29 vmcnt(0); T=30 lgkm-only; T=31 MFMA-only.
struct Frags { long long a[8]; long long b[4]; };

__device__ __forceinline__ void ld_frags(const unsigned char* buf, int aOff, int bOff,
                                         Frags& f) {
    #pragma unroll
    for (int fm = 0; fm < 8; ++fm)
        f.a[fm] = *reinterpret_cast<const long long*>(buf + aOff + fm * 512);
    #pragma unroll
    for (int fn = 0; fn < 4; ++fn)
        f.b[fn] = *reinterpret_cast<const long long*>(buf + 8192 + bOff + fn * 512);
}

__device__ __forceinline__ void do_mfma(const Frags& f, f32x4 (&acc)[8][4]) {
    __builtin_amdgcn_s_setprio(1);
    #pragma unroll
    for (int fm = 0; fm < 8; ++fm)
        #pragma unroll
        for (int fn = 0; fn < 4; ++fn)
            acc[fm][fn] = __builtin_amdgcn_mfma_f32_16x16x32_fp8_fp8(
                f.a[fm], f.b[fn], acc[fm][fn], 0, 0, 0);
    __builtin_amdgcn_s_setprio(0);
}

template<bool STG, int WE>   // WE: 2 steady, 0 at T=29, -1 lgkm-only at T=30
__device__ __forceinline__ void window(int T, unsigned char* lds,
    Frags& use, Frags& nxt,
    const unsigned char* srcA, const unsigned char* srcB,
    int aOff, int bOff, int t16, f32x4 (&acc)[8][4]) {

    ld_frags(lds + ((T + 1) % 3) * 16384, aOff, bOff, nxt);
    if (STG) {
        unsigned char* buf = lds + (T % 3) * 16384;
        load_lds16(srcA + (T + 3) * 8192, buf + t16);
        load_lds16(srcB + (T + 3) * 8192, buf + 8192 + t16);
    }
    do_mfma(use, acc);
    if (WE == 2)      asm volatile("s_waitcnt vmcnt(2)" ::: "memory");
    else if (WE == 0) asm volatile("s_waitcnt vmcnt(0)" ::: "memory");
    asm volatile("s_waitcnt lgkmcnt(0)" ::: "memory");
    __builtin_amdgcn_sched_barrier(0);
    if (WE >= 0) __builtin_amdgcn_s_barrier();
}

__global__ __launch_bounds__(512, 2)
void gemm_hinge(const unsigned char* __restrict__ A,
                const unsigned char* __restrict__ Bq,
                const float* __restrict__ pos,
                float* __restrict__ out) {
    __shared__ __align__(16) unsigned char lds[49152];

    const int tid  = threadIdx.x;
    const int lane = tid & 63;
    const int wave = tid >> 6;

    // XCD map: grid 512 = 16 bm x 32 bn tiles; 8x8 tile square per XCD.
    const int bid = blockIdx.x;
    const int x   = bid & 7;
    const int idx = bid >> 3;
    const int bm = ((x & 1) * 8 + (idx & 7));        // m-tile index (x256)
    const int bn = ((x >> 1) * 8 + (idx >> 3));      // n-tile index (x256)

    const int wr = wave >> 2, wc = wave & 3;         // 2x4 waves, 128x64 each
    const int aOff = wr * 4096 + lane * 8;           // frag base within A region
    const int bOff = wc * 2048 + lane * 8;           // frag base within B region

    const int t16 = tid * 16;
    const unsigned char* srcA = A  + (size_t)bm * PANEL + t16;
    const unsigned char* srcB = Bq + (size_t)bn * PANEL + t16;

    f32x4 acc[8][4];
    #pragma unroll
    for (int fm = 0; fm < 8; ++fm)
        #pragma unroll
        for (int fn = 0; fn < 4; ++fn)
            acc[fm][fn] = (f32x4){0.f, 0.f, 0.f, 0.f};

    Frags fA, fB;

    // prologue: tiles 0,1,2 -> buf0,1,2 (2 loads each, per-thread order A,B)
    #pragma unroll
    for (int t = 0; t < 3; ++t) {
        load_lds16(srcA + t * 8192, lds + t * 16384 + t16);
        load_lds16(srcB + t * 8192, lds + t * 16384 + 8192 + t16);
    }
    asm volatile("s_waitcnt vmcnt(4)" ::: "memory");     // tile 0 landed
    __builtin_amdgcn_sched_barrier(0);
    __builtin_amdgcn_s_barrier();                        // tile 0 published
    ld_frags(lds, aOff, bOff, fA);                       // tile 0 frags
    asm volatile("s_waitcnt vmcnt(2) lgkmcnt(0)" ::: "memory");  // tile 1 landed
    __builtin_amdgcn_sched_barrier(0);
    __builtin_amdgcn_s_barrier();                        // tile 1 published

    #pragma unroll 1
    for (int T = 0; T < 28; T += 2) {
        window<true, 2>(T,     lds, fA, fB, srcA, srcB, aOff, bOff, t16, acc);
        window<true, 2>(T + 1, lds, fB, fA, srcA, srcB, aOff, bOff, t16, acc);
    }
    window<true,  2>(28, lds, fA, fB, srcA, srcB, aOff, bOff, t16, acc);
    window<false, 0>(29, lds, fB, fA, srcA, srcB, aOff, bOff, t16, acc);
    window<false,-1>(30, lds, fA, fB, srcA, srcB, aOff, bOff, t16, acc);
    do_mfma(fB, acc);                                    // tile 31

    // ---- fused hinge epilogue ----
    // C/D: row = bm*256 + wr*128 + fm*16 + (lane>>4)*4 + j ; col fixed per lane
    float lsum = 0.f;
    #pragma unroll
    for (int fm = 0; fm < 8; ++fm) {
        const float4 p4 = *reinterpret_cast<const float4*>(
            pos + bm * 256 + wr * 128 + fm * 16 + (lane >> 4) * 4);
        const float pj[4] = {p4.x, p4.y, p4.z, p4.w};
        #pragma unroll
        for (int fn = 0; fn < 4; ++fn)
            #pragma unroll
            for (int j = 0; j < 4; ++j)
                lsum += fmaxf(DELTA_M - pj[j] + acc[fm][fn][j], 0.f);
    }
    #pragma unroll
    for (int off = 32; off; off >>= 1) lsum += __shfl_down(lsum, off);
    __syncthreads();                    // all tiles consumed; LDS reusable
    float* red = reinterpret_cast<float*>(lds);
    if (lane == 0) red[wave] = lsum;
    __syncthreads();
    if (tid == 0) {
        float s = 0.f;
        #pragma unroll
        for (int w = 0; w < 8; ++w) s += red[w];
        atomicAdd(out, s);
    }
}

extern "C" void kernel_launch(void* const* d_in, const int* in_sizes, int n_in,
                              void* d_out, int out_size, void* d_ws, size_t ws_size,
                              hipStream_t stream) {
    const float* q     = (const float*)d_in[0];
    const float* k     = (const float*)d_in[1];
    const float* queue = (const float*)d_in[2];
    float* out = (float*)d_out;

    // workspace: qn fp8 panels (4 MB) | qun fp8 panels (8 MB) | pos (16 KB)
    unsigned char* qn  = (unsigned char*)d_ws;
    unsigned char* qun = qn + (size_t)B_ROWS * DDIM;
    float* pos = (float*)(qun + (size_t)N_ROWS * DDIM);

    norm_kernel<<<(B_ROWS + N_ROWS) / 4, 256, 0, stream>>>(q, k, queue, qn, qun, pos, out);
    gemm_hinge<<<(B_ROWS / 256) * (N_ROWS / 256), 512, 0, stream>>>(qn, qun, pos, out);
}